// Round 13
// baseline (88.691 us; speedup 1.0000x reference)
//
#include <hip/hip_runtime.h>

#define NB 8
#define NS 1024
#define NH 8
#define NMONO 56    // monomials (a,b,c), a+b+c <= 5, graded order

// ---------------------------------------------------------------------------
// Quantum layer collapsed analytically (verified R3-R12): c_j = cos(x_j+th_j),
//   meas[0] = c1..c7, meas[w>=1] = c0..cw;  q = meas[0:3]/8 (|q_i|<=0.125),
//   k = meas[3:6] (|k_i|<=1), v = meas[6:8].
// Linear attention via deg-5 Taylor of e^{q.k} (|q.k|<=0.375, rel err 8e-6):
// e^{q.k} ~= sum_{a+b+c<=5} [q^abc/(a!b!c!)] * k^abc.  Moments M^w = sum_t
// k^abc w_t, w in {1,v0,v1}; att = phi(q).M^v / phi(q).M^1.  VERIFIED R9-R12.
//
// R13: ONE kernel, ZERO workspace. R10-R12 showed in-kernel restructuring is
// neutral at ~69us: residual ~27us = 2 kernel nodes x (ramp+gap ~4-6us) +
// latency-exposed tiny dispatches. Each block recomputes its batch's 8-h
// moments itself (~6.3us VALU redundancy) -> no cross-block dependency,
// no part[] round-trip, single graph node.
// R9 lesson: register arrays must scalarize -> constexpr tables, manual ch
// unroll (no pointer-to-reg-array), launch_bounds(256) => 512 VGPR cap, no
// spill. R5 lesson: no spin grid-barriers (~65us). LDS 87KB forces 1 blk/CU
// (2 blks would need 174KB > 160KB) so all 256 blocks land on distinct CUs.
// absmax 4.8828e-4 is the harness bf16-ref floor (bit-identical R3-R12).
// ---------------------------------------------------------------------------

// graded enumeration; mono[i] = mono[PRED[i]] * var[VARI[i]] (folds at CT)
constexpr int PRED[NMONO] = {
    0,
    0, 0, 0,
    1, 2, 3, 2, 3, 3,
    4, 5, 6, 7, 8, 9, 7, 8, 9, 9,
    10,11,12,13,14,15,16,17,18,19,16,17,18,19,19,
    20,21,22,23,24,25,26,27,28,29,30,31,32,33,34,30,31,32,33,34,34};
constexpr int VARI[NMONO] = {
    0,
    0, 1, 2,
    0, 0, 0, 1, 1, 2,
    0, 0, 0, 0, 0, 0, 1, 1, 1, 2,
    0, 0, 0, 0, 0, 0, 0, 0, 0, 0, 1, 1, 1, 1, 2,
    0, 0, 0, 0, 0, 0, 0, 0, 0, 0, 0, 0, 0, 0, 0, 1, 1, 1, 1, 1, 2};
#define F6 0.166666666666667f
#define F12 0.0833333333333333f
#define F24 0.0416666666666667f
#define F120 0.00833333333333333f
constexpr float COEF[NMONO] = {          // 1/(a! b! c!)
    1.f,
    1.f, 1.f, 1.f,
    0.5f, 1.f, 1.f, 0.5f, 1.f, 0.5f,
    F6, 0.5f, 0.5f, 0.5f, 1.f, 0.5f, F6, 0.5f, 0.5f, F6,
    F24, F6, F6, 0.25f, 0.5f, 0.25f, F6, 0.5f, 0.5f, F6, F24, F6, 0.25f, F6, F24,
    F120, F24, F24, F12, F6, F12, F12, 0.25f, 0.25f, F12, F24, F6, 0.25f, F6, F24,
    F120, F24, F12, F12, F24, F120};

// block = (b = bid>>5, 32-s chunk). 256 threads = 4 waves.
// Phase 1: wave w computes moments for h = 2w and 2w+1 (all 1024 t, lane
//   covers 16 t), 3 channels single-pass (tree once, 3 acc arrays in regs);
//   per-channel LDS-transpose reduce (stride 73, conflict-free) -> Mh.
// Phase 2: thread (h = tid>>5, sl = tid&31): q-monomials + 3 dots vs Mh.
// Phase 3: projection (32,16)@W^T + bias -> out (coalesced f32).
__global__ __launch_bounds__(256) void mhaq_kernel(
        const float* __restrict__ x, const float* __restrict__ theta,
        const float* __restrict__ W, const float* __restrict__ bias,
        float* __restrict__ out) {
    __shared__ float red[4][64][73];               // 74.8 KB (wave-private)
    __shared__ __align__(16) float Mh[8][176];     // [h][ch*56+i]  5.6 KB
    __shared__ float WtL[16 * 65];                 // 4.2 KB
    __shared__ float biasL[64];
    __shared__ float attL[32][17];                 // 2.2 KB   => total ~87 KB

    const int tid = threadIdx.x;
    const int b = blockIdx.x >> 5;
    const int sc = blockIdx.x & 31;
    const int s0 = sc * 32;

    // stage W^T / bias (consumed in phase 3; phase-1 syncs cover the hazard)
    for (int i = tid; i < 1024; i += 256)
        WtL[(i & 15) * 65 + (i >> 4)] = W[i];
    if (tid < 64) biasL[tid] = bias[tid];

    float th[8];
#pragma unroll
    for (int j = 0; j < 8; ++j) th[j] = theta[j];

    const int w = tid >> 6, l = tid & 63;

    // ---------------- phase 1: per-batch moments, 2 h per wave ----------------
#pragma unroll 1
    for (int hh = 0; hh < 2; ++hh) {
        const int h = 2 * w + hh;

        float acc1[NMONO], accA[NMONO], accB[NMONO];
#pragma unroll
        for (int i = 0; i < NMONO; ++i) { acc1[i] = 0.f; accA[i] = 0.f; accB[i] = 0.f; }

#pragma unroll 1
        for (int step = 0; step < 16; ++step) {
            int t = step * 64 + l;
            const float4* xp = (const float4*)(x + ((size_t)(b * NS + t)) * 64 + h * 8);
            float4 lo = xp[0], hi = xp[1];
            float c0 = __cosf(lo.x + th[0]);
            float c1 = __cosf(lo.y + th[1]);
            float c2 = __cosf(lo.z + th[2]);
            float c3 = __cosf(lo.w + th[3]);
            float c4 = __cosf(hi.x + th[4]);
            float c5 = __cosf(hi.y + th[5]);
            float c6 = __cosf(hi.z + th[6]);
            float c7 = __cosf(hi.w + th[7]);
            float k0 = ((c0 * c1) * c2) * c3;      // m3
            float k1 = k0 * c4;                    // m4
            float k2 = k1 * c5;                    // m5
            float v0 = k2 * c6;                    // m6
            float v1 = v0 * c7;                    // m7

            float mono[NMONO];
            mono[0] = 1.f;
            acc1[0] += 1.f;
            accA[0] += v0;
            accB[0] += v1;
#pragma unroll
            for (int i = 1; i < NMONO; ++i) {
                float var = (VARI[i] == 0) ? k0 : ((VARI[i] == 1) ? k1 : k2);
                mono[i] = mono[PRED[i]] * var;     // PRED[i] folds to a literal
                acc1[i] += mono[i];
                accA[i] = fmaf(mono[i], v0, accA[i]);
                accB[i] = fmaf(mono[i], v1, accB[i]);
            }
        }

        // channel 0 (weight 1)
#pragma unroll
        for (int i = 0; i < NMONO; ++i) red[w][l][i] = acc1[i];
        __syncthreads();
        if (l < NMONO) {
            float s = 0.f;
#pragma unroll
            for (int r = 0; r < 64; ++r) s += red[w][r][l];
            Mh[h][l] = s * COEF[l];
        }
        __syncthreads();
        // channel 1 (weight v0)
#pragma unroll
        for (int i = 0; i < NMONO; ++i) red[w][l][i] = accA[i];
        __syncthreads();
        if (l < NMONO) {
            float s = 0.f;
#pragma unroll
            for (int r = 0; r < 64; ++r) s += red[w][r][l];
            Mh[h][56 + l] = s * COEF[l];
        }
        __syncthreads();
        // channel 2 (weight v1)
#pragma unroll
        for (int i = 0; i < NMONO; ++i) red[w][l][i] = accB[i];
        __syncthreads();
        if (l < NMONO) {
            float s = 0.f;
#pragma unroll
            for (int r = 0; r < 64; ++r) s += red[w][r][l];
            Mh[h][112 + l] = s * COEF[l];
        }
        __syncthreads();
    }

    // ---------------- phase 2: eval 32 s x 8 h ----------------
    {
        const int h = tid >> 5, sl = tid & 31;
        const int s = s0 + sl;
        const float4* xp = (const float4*)(x + ((size_t)(b * NS + s)) * 64 + h * 8);
        float4 lo = xp[0], hi = xp[1];
        float c0 = __cosf(lo.x + th[0]);
        float c1 = __cosf(lo.y + th[1]);
        float c2 = __cosf(lo.z + th[2]);
        float c3 = __cosf(lo.w + th[3]);
        float c4 = __cosf(hi.x + th[4]);
        float c5 = __cosf(hi.y + th[5]);
        float c6 = __cosf(hi.z + th[6]);
        float c7 = __cosf(hi.w + th[7]);
        float m1 = c0 * c1;
        float m2 = m1 * c2;
        float m0 = ((c1 * c2) * (c3 * c4)) * ((c5 * c6) * c7);
        float q0 = m0 * 0.125f, q1 = m1 * 0.125f, q2 = m2 * 0.125f;

        float mono[NMONO];
        mono[0] = 1.f;
#pragma unroll
        for (int i = 1; i < NMONO; ++i)
            mono[i] = mono[PRED[i]] * ((VARI[i] == 0) ? q0 : ((VARI[i] == 1) ? q1 : q2));

        const float4* MS = (const float4*)&Mh[h][0];
        const float4* MA = (const float4*)&Mh[h][56];
        const float4* MB = (const float4*)&Mh[h][112];
        float aS = 0.f, aA = 0.f, aB = 0.f;
#pragma unroll
        for (int g = 0; g < 14; ++g) {
            float4 ms = MS[g], ma = MA[g], mb = MB[g];
            float p0 = mono[g * 4 + 0], p1 = mono[g * 4 + 1];
            float p2 = mono[g * 4 + 2], p3 = mono[g * 4 + 3];
            aS = fmaf(p0, ms.x, aS); aS = fmaf(p1, ms.y, aS);
            aS = fmaf(p2, ms.z, aS); aS = fmaf(p3, ms.w, aS);
            aA = fmaf(p0, ma.x, aA); aA = fmaf(p1, ma.y, aA);
            aA = fmaf(p2, ma.z, aA); aA = fmaf(p3, ma.w, aA);
            aB = fmaf(p0, mb.x, aB); aB = fmaf(p1, mb.y, aB);
            aB = fmaf(p2, mb.z, aB); aB = fmaf(p3, mb.w, aB);
        }
        float inv = 1.0f / aS;
        attL[sl][2 * h]     = aA * inv;
        attL[sl][2 * h + 1] = aB * inv;
    }
    __syncthreads();

    // ---------------- phase 3: projection (32,16)@W^T + bias ----------------
    {
        const int e = tid & 63, rr = tid >> 6;
#pragma unroll
        for (int j = 0; j < 8; ++j) {
            int row = rr * 8 + j;
            float acc = biasL[e];
#pragma unroll
            for (int jj = 0; jj < 16; ++jj)
                acc = fmaf(attL[row][jj], WtL[jj * 65 + e], acc);
            out[((size_t)(b * NS + s0 + row)) * 64 + e] = acc;
        }
    }
}

extern "C" void kernel_launch(void* const* d_in, const int* in_sizes, int n_in,
                              void* d_out, int out_size, void* d_ws, size_t ws_size,
                              hipStream_t stream) {
    const float* x     = (const float*)d_in[0];
    const float* theta = (const float*)d_in[1];
    const float* W     = (const float*)d_in[2];
    const float* bias  = (const float*)d_in[3];
    float* out = (float*)d_out;

    (void)d_ws; (void)ws_size;   // zero-workspace design (single graph node)
    mhaq_kernel<<<dim3(NB * 32), dim3(256), 0, stream>>>(x, theta, W, bias, out);
}